// Round 10
// baseline (959.449 us; speedup 1.0000x reference)
//
#include <hip/hip_runtime.h>
#include <math.h>

#define T_LEN 32768
#define NB 4
#define NC 64
#define NL 18
#define TILE_T 64

typedef __attribute__((ext_vector_type(8))) short s16x8;
typedef __attribute__((ext_vector_type(4))) float f32x4;
#define MFMA_F16 __builtin_amdgcn_mfma_f32_16x16x32_f16

__device__ inline unsigned short f2h(float f) {
    _Float16 h = (_Float16)f;       // RNE
    return __builtin_bit_cast(unsigned short, h);
}
__device__ inline unsigned pack_h2(float a, float b) {
    return (unsigned)f2h(a) | ((unsigned)f2h(b) << 16);
}
__device__ inline float h2f(unsigned short u) {
    return (float)__builtin_bit_cast(_Float16, u);
}
__device__ inline float fast_sigmoid(float x) {
    return __builtin_amdgcn_rcpf(1.f + __expf(-x));
}
__device__ inline float fast_tanh(float x) {
    return 1.f - 2.f * __builtin_amdgcn_rcpf(1.f + __expf(2.f * x));
}

// ------------------------------------------------------------------
// prep: weights -> fp16:
//   Wh [L][128co][192K] (K=k*64+ci); Wr [L][64co][64ci];
//   out init = mix_b; zerobuf = 0
// ------------------------------------------------------------------
__global__ void prep_kernel(const float* __restrict__ hid_w,
                            const float* __restrict__ res_w,
                            const float* __restrict__ mix_b,
                            unsigned short* __restrict__ Wh,
                            unsigned short* __restrict__ Wr,
                            float* __restrict__ out,
                            float* __restrict__ zerobuf) {
    const int nW1 = NL * 128 * 192;        // 442368
    const int nW2 = NL * 64 * 64;          // 73728
    const int nOut = NB * T_LEN;           // 131072
    const int total = nW1 + nW2 + nOut + 32;
    for (int gid = blockIdx.x * blockDim.x + threadIdx.x; gid < total;
         gid += gridDim.x * blockDim.x) {
        if (gid < nW1) {
            int K = gid % 192;
            int co = (gid / 192) & 127;
            int i = gid / (192 * 128);
            int kt = K >> 6, ci = K & 63;
            Wh[gid] = f2h(hid_w[((i * 128 + co) * 64 + ci) * 3 + kt]);
        } else if (gid < nW1 + nW2) {
            int q = gid - nW1;
            int c = q & 63, co = (q >> 6) & 63, i = q >> 12;
            Wr[q] = f2h(res_w[(i * 64 + co) * 64 + c]);
        } else if (gid < nW1 + nW2 + nOut) {
            out[gid - (nW1 + nW2)] = mix_b[0];
        } else {
            zerobuf[gid - (nW1 + nW2 + nOut)] = 0.f;
        }
    }
}

// ------------------------------------------------------------------
// fused layer, single fp16 stream. 256 thr = 4 waves; tile = (b, 64 t).
// LDS overlay: Gs lives in dead X rows (UNI ? 128.. : 0..63), OutH in
// (UNI ? 0..63 : 64..127). Extra pre-gating barrier protects the overlay.
// Total LDS ~25.6KB -> 6 blocks/CU (was 4) for more loads in flight.
// ------------------------------------------------------------------
template <int DIL, bool FIRST, bool LAST>
__launch_bounds__(256, 6)
__global__ void layer_kernel(const unsigned short* __restrict__ actH, // fp16 in
                             unsigned short* __restrict__ outH,       // fp16 out
                             const unsigned short* __restrict__ Wh, // [128][192]
                             const float* __restrict__ hb,          // [128]
                             const unsigned short* __restrict__ Wr, // [64][64]
                             const float* __restrict__ rb,          // [64]
                             const float* __restrict__ mw,          // [64]
                             float* __restrict__ skip,              // [B][T]
                             const float* __restrict__ zerobuf,
                             const float* __restrict__ x,           // [B][T]
                             const float* __restrict__ in_w,        // [64]
                             const float* __restrict__ in_b) {      // [64]
    constexpr bool UNI = (DIL < 64);
    constexpr int R = UNI ? (64 + 2 * DIL) : 192;   // staged rows
    constexpr int SLOTS = R * 8;                     // 16B chunks
    constexpr int JMAX = (SLOTS + 255) / 256;        // lds-load instrs/wave
    constexpr int GS_BASE = (UNI ? 128 : 0) * 128;   // Gs region byte base
    constexpr int OUT_BASE = (UNI ? 0 : 64) * 128;   // OutH region byte base

    __shared__ uint4 Xs[1536];   // 192 rows x 128B; Gs/OutH overlaid
    __shared__ float Sk[256];    // skip partials [w][t]
    char* lds = (char*)Xs;

    const int tid = threadIdx.x;
    const int w = tid >> 6;
    const int l = tid & 63;
    const int lo = l & 15;
    const int hi = l >> 4;
    const int b = blockIdx.y;
    const int tile = (blockIdx.x & 7) * 64 + (blockIdx.x >> 3);  // XCD swizzle
    const int t0 = tile * TILE_T;
    const int m0 = 16 * w;
    const int c0 = m0 + 4 * hi;

    const unsigned short* actB = actH + (size_t)b * T_LEN * NC;
    const float* xB = x + (size_t)b * T_LEN;

    // ---- stage X tile into LDS (swizzled [row][ci] fp16, 128B rows) ----
    if (FIRST) {
        // input conv on the fly: row r -> t = t0 + r - 2*DIL; t<0 -> ZERO
#pragma unroll
        for (int j = 0; j < JMAX; j++) {
            int p = j * 256 + tid;
            if (p < SLOTS) {
                int row = p >> 3, ch = p & 7;
                int tg = t0 + row - 2 * DIL;
                unsigned uu[4] = {0u, 0u, 0u, 0u};
                if (tg >= 0) {
                    float a = xB[tg];
#pragma unroll
                    for (int e = 0; e < 4; e++) {
                        float v0 = a * in_w[ch * 8 + 2 * e] + in_b[ch * 8 + 2 * e];
                        float v1 = a * in_w[ch * 8 + 2 * e + 1] + in_b[ch * 8 + 2 * e + 1];
                        uu[e] = pack_h2(v0, v1);
                    }
                }
                int byte = (row * 128 + ch * 16) ^ ((row & 7) << 4);
                *(uint4*)(lds + byte) = make_uint4(uu[0], uu[1], uu[2], uu[3]);
            }
        }
    } else {
        // async: fp16 stream -> LDS, source pre-swizzled, dest linear
#pragma unroll
        for (int j = 0; j < JMAX; j++) {
            int s = (w * JMAX + j) * 64 + l;
            const void* src;
            if (s >= SLOTS) {
                src = (const void*)(zerobuf + (s & 7) * 4);
            } else {
                int row = s >> 3, ch = s & 7;
                int chunk = ch ^ (row & 7);
                int tg = t0 + (UNI ? (row - 2 * DIL)
                                   : (((row >> 6) - 2) * DIL + (row & 63)));
                src = (tg >= 0) ? (const void*)(actB + (size_t)tg * 64 + chunk * 8)
                                : (const void*)(zerobuf + chunk * 4);
            }
            __builtin_amdgcn_global_load_lds(
                (const __attribute__((address_space(1))) unsigned int*)src,
                (__attribute__((address_space(3))) unsigned int*)(lds +
                                                        (w * JMAX + j) * 1024),
                16, 0, 0);
        }
    }

    // ---- W fragments -> registers ----
    s16x8 AH[2][6];
    s16x8 AR[2];
#pragma unroll
    for (int mt = 0; mt < 2; mt++) {
        const unsigned short* wp = Wh + (size_t)(m0 + 64 * mt + lo) * 192;
#pragma unroll
        for (int s = 0; s < 6; s++)
            AH[mt][s] = *(const s16x8*)(wp + 32 * s + 8 * hi);
    }
    if (!LAST) {
#pragma unroll
        for (int s = 0; s < 2; s++)
            AR[s] = *(const s16x8*)(Wr + (size_t)(m0 + lo) * 64 + 32 * s + 8 * hi);
    }

    float bA[4], bB[4], rbv[4];
#pragma unroll
    for (int r = 0; r < 4; r++) {
        bA[r] = hb[c0 + r];
        bB[r] = hb[64 + c0 + r];
        rbv[r] = LAST ? 0.f : rb[c0 + r];
    }
    const float4 mw4 = *(const float4*)(mw + c0);

    __syncthreads();   // staging (+vmcnt drain) complete

    // ---- hid GEMM: acc[mt][nt] over K=192 (3 taps x 64 ci) ----
    f32x4 acc[2][4];
#pragma unroll
    for (int mt = 0; mt < 2; mt++)
#pragma unroll
        for (int nt = 0; nt < 4; nt++)
            acc[mt][nt] = (f32x4){0.f, 0.f, 0.f, 0.f};

#pragma unroll
    for (int s = 0; s < 6; s++) {
        const int tap = s >> 1, half = s & 1;
#pragma unroll
        for (int nt = 0; nt < 4; nt++) {
            int t = 16 * nt + lo;
            int row = UNI ? (t + tap * DIL) : (tap * 64 + t);
            int byte = (row * 128 + half * 64 + hi * 16) ^ ((row & 7) << 4);
            s16x8 bx = __builtin_bit_cast(s16x8, *(const uint4*)(lds + byte));
            acc[0][nt] = MFMA_F16(AH[0][s], bx, acc[0][nt], 0, 0, 0);
            acc[1][nt] = MFMA_F16(AH[1][s], bx, acc[1][nt], 0, 0, 0);
        }
    }

    // ---- residual input from LDS tap-2 rows (tile itself) ----
    float4 inp[4];
    if (!LAST) {
#pragma unroll
        for (int nt = 0; nt < 4; nt++) {
            int t = 16 * nt + lo;
            int rowI = UNI ? (t + 2 * DIL) : (128 + t);
            int byteI = (rowI * 128 + c0 * 2) ^ ((rowI & 7) << 4);
            uint2 hv = *(const uint2*)(lds + byteI);
            inp[nt] = make_float4(h2f((unsigned short)(hv.x & 0xffff)),
                                  h2f((unsigned short)(hv.x >> 16)),
                                  h2f((unsigned short)(hv.y & 0xffff)),
                                  h2f((unsigned short)(hv.y >> 16)));
        }
    }

    __syncthreads();   // all X reads done -> safe to overlay Gs writes

    // ---- gating -> Gs (overlay) + skip partials (shfl reduce -> Sk) ----
#pragma unroll
    for (int nt = 0; nt < 4; nt++) {
        float g[4];
#pragma unroll
        for (int r = 0; r < 4; r++) {
            float hA = acc[0][nt][r] + bA[r];
            float hB = acc[1][nt][r] + bB[r];
            g[r] = fast_tanh(hA) * fast_sigmoid(hB);
        }
        int t = 16 * nt + lo;
        if (!LAST) {
            int byte = (t * 128 + c0 * 2) ^ ((t & 7) << 4);
            *(uint2*)(lds + GS_BASE + byte) =
                make_uint2(pack_h2(g[0], g[1]), pack_h2(g[2], g[3]));
        }
        float sk = g[0] * mw4.x + g[1] * mw4.y + g[2] * mw4.z + g[3] * mw4.w;
        sk += __shfl_xor(sk, 16, 64);
        sk += __shfl_xor(sk, 32, 64);
        if (hi == 0) Sk[w * 64 + nt * 16 + lo] = sk;
    }
    __syncthreads();

    if (LAST) {
        if (tid < 64) {
            float s2 = Sk[tid] + Sk[64 + tid] + Sk[128 + tid] + Sk[192 + tid];
            skip[(size_t)b * T_LEN + t0 + tid] += s2;
        }
        return;
    }

    // ---- res GEMM over K=64 (reads Gs overlay) ----
    f32x4 acc2[4];
#pragma unroll
    for (int nt = 0; nt < 4; nt++) acc2[nt] = (f32x4){0.f, 0.f, 0.f, 0.f};
#pragma unroll
    for (int s = 0; s < 2; s++) {
#pragma unroll
        for (int nt = 0; nt < 4; nt++) {
            int t = 16 * nt + lo;
            int byte = (t * 128 + s * 64 + hi * 16) ^ ((t & 7) << 4);
            s16x8 bg = __builtin_bit_cast(
                s16x8, *(const uint4*)(lds + GS_BASE + byte));
            acc2[nt] = MFMA_F16(AR[s], bg, acc2[nt], 0, 0, 0);
        }
    }

    // ---- out-stage into OutH overlay (disjoint from Gs region) ----
    char* OutH = lds + OUT_BASE;
#pragma unroll
    for (int nt = 0; nt < 4; nt++) {
        int t = 16 * nt + lo;
        float ox = acc2[nt][0] + rbv[0] + inp[nt].x;
        float oy = acc2[nt][1] + rbv[1] + inp[nt].y;
        float oz = acc2[nt][2] + rbv[2] + inp[nt].z;
        float ow = acc2[nt][3] + rbv[3] + inp[nt].w;
        int byteB = (t * 128 + c0 * 2) ^ ((t & 7) << 4);
        *(uint2*)(OutH + byteB) = make_uint2(pack_h2(ox, oy), pack_h2(oz, ow));
    }

    // ---- skip: one plain += per t ----
    if (tid < 64) {
        float s2 = Sk[tid] + Sk[64 + tid] + Sk[128 + tid] + Sk[192 + tid];
        skip[(size_t)b * T_LEN + t0 + tid] += s2;
    }
    __syncthreads();

    // ---- coalesced copy-out: full 128B lines ----
    unsigned short* gH = outH + (size_t)b * T_LEN * NC + (size_t)t0 * 64;
#pragma unroll
    for (int i = 0; i < 2; i++) {
        int u = i * 256 + tid;          // 512 uint4 = 8 KB
        int t = u >> 3, ch = u & 7;
        uint4 v = *(const uint4*)(OutH + t * 128 + ((ch ^ (t & 7)) << 4));
        ((uint4*)gH)[u] = v;
    }
}

// ------------------------------------------------------------------
extern "C" void kernel_launch(void* const* d_in, const int* in_sizes, int n_in,
                              void* d_out, int out_size, void* d_ws, size_t ws_size,
                              hipStream_t stream) {
    const float* x     = (const float*)d_in[0];
    const float* in_w  = (const float*)d_in[1];
    const float* in_b  = (const float*)d_in[2];
    const float* hid_w = (const float*)d_in[3];
    const float* hid_b = (const float*)d_in[4];
    const float* res_w = (const float*)d_in[5];
    const float* res_b = (const float*)d_in[6];
    const float* mix_w = (const float*)d_in[7];
    const float* mix_b = (const float*)d_in[8];
    float* out = (float*)d_out;

    const size_t actN = (size_t)NB * T_LEN * NC;  // 8388608
    unsigned short* H0 = (unsigned short*)d_ws;
    unsigned short* H1 = H0 + actN;
    unsigned short* Wh = H1 + actN;
    unsigned short* Wr = Wh + (size_t)NL * 128 * 192;
    float* zerobuf = (float*)(Wr + (size_t)NL * 64 * 64);

    prep_kernel<<<512, 256, 0, stream>>>(hid_w, res_w, mix_b, Wh, Wr, out,
                                         zerobuf);

    static const int dils[NL] = {1, 2, 4, 8, 16, 32, 64, 128, 256,
                                 1, 2, 4, 8, 16, 32, 64, 128, 256};
    const unsigned short* srcH = H0;
    unsigned short* dstH = H1;
    dim3 grid(T_LEN / TILE_T, NB);

#define LL(D, F, L)                                                           \
    layer_kernel<D, F, L><<<grid, 256, 0, stream>>>(                          \
        srcH, dstH, Wh + (size_t)i * 128 * 192, hid_b + (size_t)i * 128,      \
        Wr + (size_t)i * 64 * 64, res_b + (size_t)i * 64,                     \
        mix_w + (size_t)i * 64, out, zerobuf, x, in_w, in_b)

    for (int i = 0; i < NL; i++) {
        if (i == 0) {
            LL(1, true, false);
        } else if (i == NL - 1) {
            LL(256, false, true);
        } else {
            switch (dils[i]) {
                case 1:   LL(1, false, false);   break;
                case 2:   LL(2, false, false);   break;
                case 4:   LL(4, false, false);   break;
                case 8:   LL(8, false, false);   break;
                case 16:  LL(16, false, false);  break;
                case 32:  LL(32, false, false);  break;
                case 64:  LL(64, false, false);  break;
                case 128: LL(128, false, false); break;
                case 256: LL(256, false, false); break;
            }
        }
        const unsigned short* tH = srcH; srcH = dstH; dstH = (unsigned short*)tH;
    }
#undef LL
}

// Round 11
// 380.187 us; speedup vs baseline: 2.5236x; 2.5236x over previous
//
#include <hip/hip_runtime.h>
#include <math.h>

#define T_LEN 32768
#define NB 4
#define NC 64
#define NL 18
#define TILE_T 64

typedef __attribute__((ext_vector_type(8))) short s16x8;
typedef __attribute__((ext_vector_type(4))) float f32x4;
#define MFMA_F16 __builtin_amdgcn_mfma_f32_16x16x32_f16

__device__ inline unsigned short f2h(float f) {
    _Float16 h = (_Float16)f;       // RNE
    return __builtin_bit_cast(unsigned short, h);
}
__device__ inline unsigned pack_h2(float a, float b) {
    return (unsigned)f2h(a) | ((unsigned)f2h(b) << 16);
}
__device__ inline float h2f(unsigned short u) {
    return (float)__builtin_bit_cast(_Float16, u);
}
__device__ inline float fast_sigmoid(float x) {
    return __builtin_amdgcn_rcpf(1.f + __expf(-x));
}
__device__ inline float fast_tanh(float x) {
    return 1.f - 2.f * __builtin_amdgcn_rcpf(1.f + __expf(2.f * x));
}

// ------------------------------------------------------------------
// prep: weights -> fp16:
//   Wh [L][128co][192K] (K=k*64+ci); Wr [L][64co][64ci];
//   out init = mix_b; zerobuf = 0
// ------------------------------------------------------------------
__global__ void prep_kernel(const float* __restrict__ hid_w,
                            const float* __restrict__ res_w,
                            const float* __restrict__ mix_b,
                            unsigned short* __restrict__ Wh,
                            unsigned short* __restrict__ Wr,
                            float* __restrict__ out,
                            float* __restrict__ zerobuf) {
    const int nW1 = NL * 128 * 192;        // 442368
    const int nW2 = NL * 64 * 64;          // 73728
    const int nOut = NB * T_LEN;           // 131072
    const int total = nW1 + nW2 + nOut + 32;
    for (int gid = blockIdx.x * blockDim.x + threadIdx.x; gid < total;
         gid += gridDim.x * blockDim.x) {
        if (gid < nW1) {
            int K = gid % 192;
            int co = (gid / 192) & 127;
            int i = gid / (192 * 128);
            int kt = K >> 6, ci = K & 63;
            Wh[gid] = f2h(hid_w[((i * 128 + co) * 64 + ci) * 3 + kt]);
        } else if (gid < nW1 + nW2) {
            int q = gid - nW1;
            int c = q & 63, co = (q >> 6) & 63, i = q >> 12;
            Wr[q] = f2h(res_w[(i * 64 + co) * 64 + c]);
        } else if (gid < nW1 + nW2 + nOut) {
            out[gid - (nW1 + nW2)] = mix_b[0];
        } else {
            zerobuf[gid - (nW1 + nW2 + nOut)] = 0.f;
        }
    }
}

// ------------------------------------------------------------------
// fused layer, single fp16 stream. 256 thr = 4 waves; tile = (b, 64 t).
// LDS overlay: Gs lives in dead X rows (UNI ? 128.. : 0..63), OutH in
// (UNI ? 0..63 : 64..127). Extra pre-gating barrier protects the overlay.
// LDS 25.6KB -> LDS-limit 6 blocks/CU. launch_bounds stays (256,4):
// R10 showed (256,6) forces VGPR=40 < live set (AH=48) -> scratch spill
// (WRITE 17->152 MB/layer). At (256,4) the kernel compiles to ~64 VGPR,
// which allows 8 waves/SIMD VGPR-wise; runtime occupancy = LDS limit.
// ------------------------------------------------------------------
template <int DIL, bool FIRST, bool LAST>
__launch_bounds__(256, 4)
__global__ void layer_kernel(const unsigned short* __restrict__ actH, // fp16 in
                             unsigned short* __restrict__ outH,       // fp16 out
                             const unsigned short* __restrict__ Wh, // [128][192]
                             const float* __restrict__ hb,          // [128]
                             const unsigned short* __restrict__ Wr, // [64][64]
                             const float* __restrict__ rb,          // [64]
                             const float* __restrict__ mw,          // [64]
                             float* __restrict__ skip,              // [B][T]
                             const float* __restrict__ zerobuf,
                             const float* __restrict__ x,           // [B][T]
                             const float* __restrict__ in_w,        // [64]
                             const float* __restrict__ in_b) {      // [64]
    constexpr bool UNI = (DIL < 64);
    constexpr int R = UNI ? (64 + 2 * DIL) : 192;   // staged rows
    constexpr int SLOTS = R * 8;                     // 16B chunks
    constexpr int JMAX = (SLOTS + 255) / 256;        // lds-load instrs/wave
    constexpr int GS_BASE = (UNI ? 128 : 0) * 128;   // Gs region byte base
    constexpr int OUT_BASE = (UNI ? 0 : 64) * 128;   // OutH region byte base

    __shared__ uint4 Xs[1536];   // 192 rows x 128B; Gs/OutH overlaid
    __shared__ float Sk[256];    // skip partials [w][t]
    char* lds = (char*)Xs;

    const int tid = threadIdx.x;
    const int w = tid >> 6;
    const int l = tid & 63;
    const int lo = l & 15;
    const int hi = l >> 4;
    const int b = blockIdx.y;
    const int tile = (blockIdx.x & 7) * 64 + (blockIdx.x >> 3);  // XCD swizzle
    const int t0 = tile * TILE_T;
    const int m0 = 16 * w;
    const int c0 = m0 + 4 * hi;

    const unsigned short* actB = actH + (size_t)b * T_LEN * NC;
    const float* xB = x + (size_t)b * T_LEN;

    // ---- stage X tile into LDS (swizzled [row][ci] fp16, 128B rows) ----
    if (FIRST) {
        // input conv on the fly: row r -> t = t0 + r - 2*DIL; t<0 -> ZERO
#pragma unroll
        for (int j = 0; j < JMAX; j++) {
            int p = j * 256 + tid;
            if (p < SLOTS) {
                int row = p >> 3, ch = p & 7;
                int tg = t0 + row - 2 * DIL;
                unsigned uu[4] = {0u, 0u, 0u, 0u};
                if (tg >= 0) {
                    float a = xB[tg];
#pragma unroll
                    for (int e = 0; e < 4; e++) {
                        float v0 = a * in_w[ch * 8 + 2 * e] + in_b[ch * 8 + 2 * e];
                        float v1 = a * in_w[ch * 8 + 2 * e + 1] + in_b[ch * 8 + 2 * e + 1];
                        uu[e] = pack_h2(v0, v1);
                    }
                }
                int byte = (row * 128 + ch * 16) ^ ((row & 7) << 4);
                *(uint4*)(lds + byte) = make_uint4(uu[0], uu[1], uu[2], uu[3]);
            }
        }
    } else {
        // async: fp16 stream -> LDS, source pre-swizzled, dest linear
#pragma unroll
        for (int j = 0; j < JMAX; j++) {
            int s = (w * JMAX + j) * 64 + l;
            const void* src;
            if (s >= SLOTS) {
                src = (const void*)(zerobuf + (s & 7) * 4);
            } else {
                int row = s >> 3, ch = s & 7;
                int chunk = ch ^ (row & 7);
                int tg = t0 + (UNI ? (row - 2 * DIL)
                                   : (((row >> 6) - 2) * DIL + (row & 63)));
                src = (tg >= 0) ? (const void*)(actB + (size_t)tg * 64 + chunk * 8)
                                : (const void*)(zerobuf + chunk * 4);
            }
            __builtin_amdgcn_global_load_lds(
                (const __attribute__((address_space(1))) unsigned int*)src,
                (__attribute__((address_space(3))) unsigned int*)(lds +
                                                        (w * JMAX + j) * 1024),
                16, 0, 0);
        }
    }

    // ---- W fragments -> registers ----
    s16x8 AH[2][6];
    s16x8 AR[2];
#pragma unroll
    for (int mt = 0; mt < 2; mt++) {
        const unsigned short* wp = Wh + (size_t)(m0 + 64 * mt + lo) * 192;
#pragma unroll
        for (int s = 0; s < 6; s++)
            AH[mt][s] = *(const s16x8*)(wp + 32 * s + 8 * hi);
    }
    if (!LAST) {
#pragma unroll
        for (int s = 0; s < 2; s++)
            AR[s] = *(const s16x8*)(Wr + (size_t)(m0 + lo) * 64 + 32 * s + 8 * hi);
    }

    float bA[4], bB[4], rbv[4];
#pragma unroll
    for (int r = 0; r < 4; r++) {
        bA[r] = hb[c0 + r];
        bB[r] = hb[64 + c0 + r];
        rbv[r] = LAST ? 0.f : rb[c0 + r];
    }
    const float4 mw4 = *(const float4*)(mw + c0);

    __syncthreads();   // staging (+vmcnt drain) complete

    // ---- hid GEMM: acc[mt][nt] over K=192 (3 taps x 64 ci) ----
    f32x4 acc[2][4];
#pragma unroll
    for (int mt = 0; mt < 2; mt++)
#pragma unroll
        for (int nt = 0; nt < 4; nt++)
            acc[mt][nt] = (f32x4){0.f, 0.f, 0.f, 0.f};

#pragma unroll
    for (int s = 0; s < 6; s++) {
        const int tap = s >> 1, half = s & 1;
#pragma unroll
        for (int nt = 0; nt < 4; nt++) {
            int t = 16 * nt + lo;
            int row = UNI ? (t + tap * DIL) : (tap * 64 + t);
            int byte = (row * 128 + half * 64 + hi * 16) ^ ((row & 7) << 4);
            s16x8 bx = __builtin_bit_cast(s16x8, *(const uint4*)(lds + byte));
            acc[0][nt] = MFMA_F16(AH[0][s], bx, acc[0][nt], 0, 0, 0);
            acc[1][nt] = MFMA_F16(AH[1][s], bx, acc[1][nt], 0, 0, 0);
        }
    }

    // ---- residual input from LDS tap-2 rows (tile itself) ----
    float4 inp[4];
    if (!LAST) {
#pragma unroll
        for (int nt = 0; nt < 4; nt++) {
            int t = 16 * nt + lo;
            int rowI = UNI ? (t + 2 * DIL) : (128 + t);
            int byteI = (rowI * 128 + c0 * 2) ^ ((rowI & 7) << 4);
            uint2 hv = *(const uint2*)(lds + byteI);
            inp[nt] = make_float4(h2f((unsigned short)(hv.x & 0xffff)),
                                  h2f((unsigned short)(hv.x >> 16)),
                                  h2f((unsigned short)(hv.y & 0xffff)),
                                  h2f((unsigned short)(hv.y >> 16)));
        }
    }

    __syncthreads();   // all X reads done -> safe to overlay Gs writes

    // ---- gating -> Gs (overlay) + skip partials (shfl reduce -> Sk) ----
#pragma unroll
    for (int nt = 0; nt < 4; nt++) {
        float g[4];
#pragma unroll
        for (int r = 0; r < 4; r++) {
            float hA = acc[0][nt][r] + bA[r];
            float hB = acc[1][nt][r] + bB[r];
            g[r] = fast_tanh(hA) * fast_sigmoid(hB);
        }
        int t = 16 * nt + lo;
        if (!LAST) {
            int byte = (t * 128 + c0 * 2) ^ ((t & 7) << 4);
            *(uint2*)(lds + GS_BASE + byte) =
                make_uint2(pack_h2(g[0], g[1]), pack_h2(g[2], g[3]));
        }
        float sk = g[0] * mw4.x + g[1] * mw4.y + g[2] * mw4.z + g[3] * mw4.w;
        sk += __shfl_xor(sk, 16, 64);
        sk += __shfl_xor(sk, 32, 64);
        if (hi == 0) Sk[w * 64 + nt * 16 + lo] = sk;
    }
    __syncthreads();

    if (LAST) {
        if (tid < 64) {
            float s2 = Sk[tid] + Sk[64 + tid] + Sk[128 + tid] + Sk[192 + tid];
            skip[(size_t)b * T_LEN + t0 + tid] += s2;
        }
        return;
    }

    // ---- res GEMM over K=64 (reads Gs overlay) ----
    f32x4 acc2[4];
#pragma unroll
    for (int nt = 0; nt < 4; nt++) acc2[nt] = (f32x4){0.f, 0.f, 0.f, 0.f};
#pragma unroll
    for (int s = 0; s < 2; s++) {
#pragma unroll
        for (int nt = 0; nt < 4; nt++) {
            int t = 16 * nt + lo;
            int byte = (t * 128 + s * 64 + hi * 16) ^ ((t & 7) << 4);
            s16x8 bg = __builtin_bit_cast(
                s16x8, *(const uint4*)(lds + GS_BASE + byte));
            acc2[nt] = MFMA_F16(AR[s], bg, acc2[nt], 0, 0, 0);
        }
    }

    // ---- out-stage into OutH overlay (disjoint from Gs region) ----
    char* OutH = lds + OUT_BASE;
#pragma unroll
    for (int nt = 0; nt < 4; nt++) {
        int t = 16 * nt + lo;
        float ox = acc2[nt][0] + rbv[0] + inp[nt].x;
        float oy = acc2[nt][1] + rbv[1] + inp[nt].y;
        float oz = acc2[nt][2] + rbv[2] + inp[nt].z;
        float ow = acc2[nt][3] + rbv[3] + inp[nt].w;
        int byteB = (t * 128 + c0 * 2) ^ ((t & 7) << 4);
        *(uint2*)(OutH + byteB) = make_uint2(pack_h2(ox, oy), pack_h2(oz, ow));
    }

    // ---- skip: one plain += per t ----
    if (tid < 64) {
        float s2 = Sk[tid] + Sk[64 + tid] + Sk[128 + tid] + Sk[192 + tid];
        skip[(size_t)b * T_LEN + t0 + tid] += s2;
    }
    __syncthreads();

    // ---- coalesced copy-out: full 128B lines ----
    unsigned short* gH = outH + (size_t)b * T_LEN * NC + (size_t)t0 * 64;
#pragma unroll
    for (int i = 0; i < 2; i++) {
        int u = i * 256 + tid;          // 512 uint4 = 8 KB
        int t = u >> 3, ch = u & 7;
        uint4 v = *(const uint4*)(OutH + t * 128 + ((ch ^ (t & 7)) << 4));
        ((uint4*)gH)[u] = v;
    }
}

// ------------------------------------------------------------------
extern "C" void kernel_launch(void* const* d_in, const int* in_sizes, int n_in,
                              void* d_out, int out_size, void* d_ws, size_t ws_size,
                              hipStream_t stream) {
    const float* x     = (const float*)d_in[0];
    const float* in_w  = (const float*)d_in[1];
    const float* in_b  = (const float*)d_in[2];
    const float* hid_w = (const float*)d_in[3];
    const float* hid_b = (const float*)d_in[4];
    const float* res_w = (const float*)d_in[5];
    const float* res_b = (const float*)d_in[6];
    const float* mix_w = (const float*)d_in[7];
    const float* mix_b = (const float*)d_in[8];
    float* out = (float*)d_out;

    const size_t actN = (size_t)NB * T_LEN * NC;  // 8388608
    unsigned short* H0 = (unsigned short*)d_ws;
    unsigned short* H1 = H0 + actN;
    unsigned short* Wh = H1 + actN;
    unsigned short* Wr = Wh + (size_t)NL * 128 * 192;
    float* zerobuf = (float*)(Wr + (size_t)NL * 64 * 64);

    prep_kernel<<<512, 256, 0, stream>>>(hid_w, res_w, mix_b, Wh, Wr, out,
                                         zerobuf);

    static const int dils[NL] = {1, 2, 4, 8, 16, 32, 64, 128, 256,
                                 1, 2, 4, 8, 16, 32, 64, 128, 256};
    const unsigned short* srcH = H0;
    unsigned short* dstH = H1;
    dim3 grid(T_LEN / TILE_T, NB);

#define LL(D, F, L)                                                           \
    layer_kernel<D, F, L><<<grid, 256, 0, stream>>>(                          \
        srcH, dstH, Wh + (size_t)i * 128 * 192, hid_b + (size_t)i * 128,      \
        Wr + (size_t)i * 64 * 64, res_b + (size_t)i * 64,                     \
        mix_w + (size_t)i * 64, out, zerobuf, x, in_w, in_b)

    for (int i = 0; i < NL; i++) {
        if (i == 0) {
            LL(1, true, false);
        } else if (i == NL - 1) {
            LL(256, false, true);
        } else {
            switch (dils[i]) {
                case 1:   LL(1, false, false);   break;
                case 2:   LL(2, false, false);   break;
                case 4:   LL(4, false, false);   break;
                case 8:   LL(8, false, false);   break;
                case 16:  LL(16, false, false);  break;
                case 32:  LL(32, false, false);  break;
                case 64:  LL(64, false, false);  break;
                case 128: LL(128, false, false); break;
                case 256: LL(256, false, false); break;
            }
        }
        const unsigned short* tH = srcH; srcH = dstH; dstH = (unsigned short*)tH;
    }
#undef LL
}

// Round 12
// 373.885 us; speedup vs baseline: 2.5662x; 1.0169x over previous
//
#include <hip/hip_runtime.h>
#include <math.h>

#define T_LEN 32768
#define NB 4
#define NC 64
#define NL 18

typedef __attribute__((ext_vector_type(8))) short s16x8;
typedef __attribute__((ext_vector_type(4))) float f32x4;
#define MFMA_F16 __builtin_amdgcn_mfma_f32_16x16x32_f16

// raw barriers: never drain vmcnt mid-kernel (T3/T4). lgkm-only for LDS phases.
#define BAR_LGKM()                                                   \
    do {                                                             \
        asm volatile("s_waitcnt lgkmcnt(0)" ::: "memory");           \
        __builtin_amdgcn_s_barrier();                                \
        __builtin_amdgcn_sched_barrier(0);                           \
    } while (0)
#define BAR_VM(N)                                                    \
    do {                                                             \
        asm volatile("s_waitcnt vmcnt(%0) lgkmcnt(0)" ::             \
                         "i"(N) : "memory");                         \
        __builtin_amdgcn_s_barrier();                                \
        __builtin_amdgcn_sched_barrier(0);                           \
    } while (0)

__device__ inline unsigned short f2h(float f) {
    _Float16 h = (_Float16)f;       // RNE
    return __builtin_bit_cast(unsigned short, h);
}
__device__ inline unsigned pack_h2(float a, float b) {
    return (unsigned)f2h(a) | ((unsigned)f2h(b) << 16);
}
__device__ inline float h2f(unsigned short u) {
    return (float)__builtin_bit_cast(_Float16, u);
}
__device__ inline float fast_sigmoid(float x) {
    return __builtin_amdgcn_rcpf(1.f + __expf(-x));
}
__device__ inline float fast_tanh(float x) {
    return 1.f - 2.f * __builtin_amdgcn_rcpf(1.f + __expf(2.f * x));
}

// ------------------------------------------------------------------
// prep: weights -> fp16; out init = mix_b; zerobuf = 0
// ------------------------------------------------------------------
__global__ void prep_kernel(const float* __restrict__ hid_w,
                            const float* __restrict__ res_w,
                            const float* __restrict__ mix_b,
                            unsigned short* __restrict__ Wh,
                            unsigned short* __restrict__ Wr,
                            float* __restrict__ out,
                            float* __restrict__ zerobuf) {
    const int nW1 = NL * 128 * 192;        // 442368
    const int nW2 = NL * 64 * 64;          // 73728
    const int nOut = NB * T_LEN;           // 131072
    const int total = nW1 + nW2 + nOut + 32;
    for (int gid = blockIdx.x * blockDim.x + threadIdx.x; gid < total;
         gid += gridDim.x * blockDim.x) {
        if (gid < nW1) {
            int K = gid % 192;
            int co = (gid / 192) & 127;
            int i = gid / (192 * 128);
            int kt = K >> 6, ci = K & 63;
            Wh[gid] = f2h(hid_w[((i * 128 + co) * 64 + ci) * 3 + kt]);
        } else if (gid < nW1 + nW2) {
            int q = gid - nW1;
            int c = q & 63, co = (q >> 6) & 63, i = q >> 12;
            Wr[q] = f2h(res_w[(i * 64 + co) * 64 + c]);
        } else if (gid < nW1 + nW2 + nOut) {
            out[gid - (nW1 + nW2)] = mix_b[0];
        } else {
            zerobuf[gid - (nW1 + nW2 + nOut)] = 0.f;
        }
    }
}

// ------------------------------------------------------------------
// fused layer, 2-subtile pipelined. Block = 4 waves, owns 128 t (two
// 64-t subtiles). Both subtiles' global_load_lds issued up front;
// BAR_VM(JMAX) releases subtile 0 with subtile 1 still in flight
// (counted vmcnt, T3/T4). Interior barriers are lgkm-only raw
// s_barrier: __syncthreads would emit vmcnt(0) and kill the overlap.
// ------------------------------------------------------------------
template <int DIL, bool FIRST, bool LAST>
__launch_bounds__(256, 4)
__global__ void layer_kernel(const unsigned short* __restrict__ actH, // fp16 in
                             unsigned short* __restrict__ outH,       // fp16 out
                             const unsigned short* __restrict__ Wh, // [128][192]
                             const float* __restrict__ hb,          // [128]
                             const unsigned short* __restrict__ Wr, // [64][64]
                             const float* __restrict__ rb,          // [64]
                             const float* __restrict__ mw,          // [64]
                             float* __restrict__ skip,              // [B][T]
                             const float* __restrict__ zerobuf,
                             const float* __restrict__ x,           // [B][T]
                             const float* __restrict__ in_w,        // [64]
                             const float* __restrict__ in_b) {      // [64]
    constexpr bool UNI = (DIL < 64);
    constexpr int R = UNI ? (64 + 2 * DIL) : 192;   // staged rows / subtile
    constexpr int SLOTS = R * 8;                     // 16B chunks
    constexpr int JMAX = (SLOTS + 255) / 256;        // loads per wave
    constexpr int GS_BASE = (UNI ? 128 : 0) * 128;   // Gs overlay (in-region)
    constexpr int OUT_BASE = (UNI ? 0 : 64) * 128;   // OutH overlay
    constexpr int REG = 24576;                       // bytes per subtile region

    __shared__ uint4 Xs[2 * 1536];   // two 192-row regions
    __shared__ float Sk[256];        // skip partials [w][t]
    char* lds = (char*)Xs;

    const int tid = threadIdx.x;
    const int w = tid >> 6;
    const int l = tid & 63;
    const int lo = l & 15;
    const int hi = l >> 4;
    const int b = blockIdx.y;
    const int tile = (blockIdx.x & 7) * 32 + (blockIdx.x >> 3);  // XCD swizzle
    const int t0 = tile * 128;
    const int m0 = 16 * w;
    const int c0 = m0 + 4 * hi;

    const unsigned short* actB = actH + (size_t)b * T_LEN * NC;
    const float* xB = x + (size_t)b * T_LEN;

    // ---- W fragments + biases first (oldest vmem; auto-waited) ----
    s16x8 AH[2][6];
    s16x8 AR[2];
#pragma unroll
    for (int mt = 0; mt < 2; mt++) {
        const unsigned short* wp = Wh + (size_t)(m0 + 64 * mt + lo) * 192;
#pragma unroll
        for (int s = 0; s < 6; s++)
            AH[mt][s] = *(const s16x8*)(wp + 32 * s + 8 * hi);
    }
    if (!LAST) {
#pragma unroll
        for (int s = 0; s < 2; s++)
            AR[s] = *(const s16x8*)(Wr + (size_t)(m0 + lo) * 64 + 32 * s + 8 * hi);
    }
    float bA[4], bB[4], rbv[4];
#pragma unroll
    for (int r = 0; r < 4; r++) {
        bA[r] = hb[c0 + r];
        bB[r] = hb[64 + c0 + r];
        rbv[r] = LAST ? 0.f : rb[c0 + r];
    }
    const float4 mw4 = *(const float4*)(mw + c0);

    // ---- stage BOTH subtiles ----
    if (FIRST) {
        // input conv on the fly (VALU/LDS only); t<0 -> ZERO
#pragma unroll
        for (int sub = 0; sub < 2; sub++) {
            char* X = lds + sub * REG;
            const int tb = t0 + sub * 64;
#pragma unroll
            for (int j = 0; j < JMAX; j++) {
                int p = j * 256 + tid;
                if (p < SLOTS) {
                    int row = p >> 3, ch = p & 7;
                    int tg = tb + row - 2 * DIL;
                    unsigned uu[4] = {0u, 0u, 0u, 0u};
                    if (tg >= 0) {
                        float a = xB[tg];
#pragma unroll
                        for (int e = 0; e < 4; e++) {
                            float v0 = a * in_w[ch * 8 + 2 * e] + in_b[ch * 8 + 2 * e];
                            float v1 = a * in_w[ch * 8 + 2 * e + 1] + in_b[ch * 8 + 2 * e + 1];
                            uu[e] = pack_h2(v0, v1);
                        }
                    }
                    int byte = (row * 128 + ch * 16) ^ ((row & 7) << 4);
                    *(uint4*)(X + byte) = make_uint4(uu[0], uu[1], uu[2], uu[3]);
                }
            }
        }
    } else {
        // async global->LDS, source pre-swizzled, dest linear
#pragma unroll
        for (int sub = 0; sub < 2; sub++) {
            char* X = lds + sub * REG;
            const int tb = t0 + sub * 64;
#pragma unroll
            for (int j = 0; j < JMAX; j++) {
                int s = (w * JMAX + j) * 64 + l;
                const void* src;
                if (s >= SLOTS) {
                    src = (const void*)(zerobuf + (s & 7) * 4);
                } else {
                    int row = s >> 3, ch = s & 7;
                    int chunk = ch ^ (row & 7);
                    int tg = tb + (UNI ? (row - 2 * DIL)
                                       : (((row >> 6) - 2) * DIL + (row & 63)));
                    src = (tg >= 0)
                              ? (const void*)(actB + (size_t)tg * 64 + chunk * 8)
                              : (const void*)(zerobuf + chunk * 4);
                }
                __builtin_amdgcn_global_load_lds(
                    (const __attribute__((address_space(1))) unsigned int*)src,
                    (__attribute__((address_space(3))) unsigned int*)(X +
                                                        (w * JMAX + j) * 1024),
                    16, 0, 0);
            }
        }
    }

    // ---- two pipelined subtiles ----
#pragma unroll
    for (int sub = 0; sub < 2; sub++) {
        char* X = lds + sub * REG;
        const int tt0 = t0 + sub * 64;

        if (FIRST) {
            BAR_LGKM();
        } else if (sub == 0) {
            BAR_VM(JMAX);      // subtile-0 ready; subtile-1 still in flight
        } else {
            BAR_VM(0);         // subtile-1 ready
        }

        // ---- hid GEMM over K=192 ----
        f32x4 acc[2][4];
#pragma unroll
        for (int mt = 0; mt < 2; mt++)
#pragma unroll
            for (int nt = 0; nt < 4; nt++)
                acc[mt][nt] = (f32x4){0.f, 0.f, 0.f, 0.f};
#pragma unroll
        for (int s = 0; s < 6; s++) {
            const int tap = s >> 1, half = s & 1;
#pragma unroll
            for (int nt = 0; nt < 4; nt++) {
                int t = 16 * nt + lo;
                int row = UNI ? (t + tap * DIL) : (tap * 64 + t);
                int byte = (row * 128 + half * 64 + hi * 16) ^ ((row & 7) << 4);
                s16x8 bx = __builtin_bit_cast(s16x8, *(const uint4*)(X + byte));
                acc[0][nt] = MFMA_F16(AH[0][s], bx, acc[0][nt], 0, 0, 0);
                acc[1][nt] = MFMA_F16(AH[1][s], bx, acc[1][nt], 0, 0, 0);
            }
        }

        // ---- residual input from staged tap-2 rows ----
        float4 inp[4];
        if (!LAST) {
#pragma unroll
            for (int nt = 0; nt < 4; nt++) {
                int t = 16 * nt + lo;
                int rowI = UNI ? (t + 2 * DIL) : (128 + t);
                int byteI = (rowI * 128 + c0 * 2) ^ ((rowI & 7) << 4);
                uint2 hv = *(const uint2*)(X + byteI);
                inp[nt] = make_float4(h2f((unsigned short)(hv.x & 0xffff)),
                                      h2f((unsigned short)(hv.x >> 16)),
                                      h2f((unsigned short)(hv.y & 0xffff)),
                                      h2f((unsigned short)(hv.y >> 16)));
            }
        }

        BAR_LGKM();   // all X reads done -> overlay writes safe

        // ---- gating -> Gs overlay + skip partials ----
#pragma unroll
        for (int nt = 0; nt < 4; nt++) {
            float g[4];
#pragma unroll
            for (int r = 0; r < 4; r++) {
                float hA = acc[0][nt][r] + bA[r];
                float hB = acc[1][nt][r] + bB[r];
                g[r] = fast_tanh(hA) * fast_sigmoid(hB);
            }
            int t = 16 * nt + lo;
            if (!LAST) {
                int byte = (t * 128 + c0 * 2) ^ ((t & 7) << 4);
                *(uint2*)(X + GS_BASE + byte) =
                    make_uint2(pack_h2(g[0], g[1]), pack_h2(g[2], g[3]));
            }
            float sk = g[0] * mw4.x + g[1] * mw4.y + g[2] * mw4.z + g[3] * mw4.w;
            sk += __shfl_xor(sk, 16, 64);
            sk += __shfl_xor(sk, 32, 64);
            if (hi == 0) Sk[w * 64 + nt * 16 + lo] = sk;
        }
        BAR_LGKM();

        if (LAST) {
            if (tid < 64) {
                float s2 = Sk[tid] + Sk[64 + tid] + Sk[128 + tid] + Sk[192 + tid];
                skip[(size_t)b * T_LEN + tt0 + tid] += s2;
            }
            continue;
        }

        // ---- res GEMM over K=64 ----
        f32x4 acc2[4];
#pragma unroll
        for (int nt = 0; nt < 4; nt++) acc2[nt] = (f32x4){0.f, 0.f, 0.f, 0.f};
#pragma unroll
        for (int s = 0; s < 2; s++) {
#pragma unroll
            for (int nt = 0; nt < 4; nt++) {
                int t = 16 * nt + lo;
                int byte = (t * 128 + s * 64 + hi * 16) ^ ((t & 7) << 4);
                s16x8 bg = __builtin_bit_cast(
                    s16x8, *(const uint4*)(X + GS_BASE + byte));
                acc2[nt] = MFMA_F16(AR[s], bg, acc2[nt], 0, 0, 0);
            }
        }

        // ---- out-stage into OutH overlay (disjoint from Gs region) ----
        char* OutH = X + OUT_BASE;
#pragma unroll
        for (int nt = 0; nt < 4; nt++) {
            int t = 16 * nt + lo;
            float ox = acc2[nt][0] + rbv[0] + inp[nt].x;
            float oy = acc2[nt][1] + rbv[1] + inp[nt].y;
            float oz = acc2[nt][2] + rbv[2] + inp[nt].z;
            float ow = acc2[nt][3] + rbv[3] + inp[nt].w;
            int byteB = (t * 128 + c0 * 2) ^ ((t & 7) << 4);
            *(uint2*)(OutH + byteB) =
                make_uint2(pack_h2(ox, oy), pack_h2(oz, ow));
        }

        // ---- skip: one plain += per t ----
        if (tid < 64) {
            float s2 = Sk[tid] + Sk[64 + tid] + Sk[128 + tid] + Sk[192 + tid];
            skip[(size_t)b * T_LEN + tt0 + tid] += s2;
        }
        BAR_LGKM();

        // ---- coalesced copy-out: full 128B lines ----
        unsigned short* gH = outH + (size_t)b * T_LEN * NC + (size_t)tt0 * 64;
#pragma unroll
        for (int i = 0; i < 2; i++) {
            int u = i * 256 + tid;      // 512 uint4 = 8 KB
            int t = u >> 3, ch = u & 7;
            uint4 v = *(const uint4*)(OutH + t * 128 + ((ch ^ (t & 7)) << 4));
            ((uint4*)gH)[u] = v;
        }
    }
}

// ------------------------------------------------------------------
extern "C" void kernel_launch(void* const* d_in, const int* in_sizes, int n_in,
                              void* d_out, int out_size, void* d_ws, size_t ws_size,
                              hipStream_t stream) {
    const float* x     = (const float*)d_in[0];
    const float* in_w  = (const float*)d_in[1];
    const float* in_b  = (const float*)d_in[2];
    const float* hid_w = (const float*)d_in[3];
    const float* hid_b = (const float*)d_in[4];
    const float* res_w = (const float*)d_in[5];
    const float* res_b = (const float*)d_in[6];
    const float* mix_w = (const float*)d_in[7];
    const float* mix_b = (const float*)d_in[8];
    float* out = (float*)d_out;

    const size_t actN = (size_t)NB * T_LEN * NC;  // 8388608
    unsigned short* H0 = (unsigned short*)d_ws;
    unsigned short* H1 = H0 + actN;
    unsigned short* Wh = H1 + actN;
    unsigned short* Wr = Wh + (size_t)NL * 128 * 192;
    float* zerobuf = (float*)(Wr + (size_t)NL * 64 * 64);

    prep_kernel<<<512, 256, 0, stream>>>(hid_w, res_w, mix_b, Wh, Wr, out,
                                         zerobuf);

    static const int dils[NL] = {1, 2, 4, 8, 16, 32, 64, 128, 256,
                                 1, 2, 4, 8, 16, 32, 64, 128, 256};
    const unsigned short* srcH = H0;
    unsigned short* dstH = H1;
    dim3 grid(T_LEN / 128, NB);   // 256 x 4

#define LL(D, F, L)                                                           \
    layer_kernel<D, F, L><<<grid, 256, 0, stream>>>(                          \
        srcH, dstH, Wh + (size_t)i * 128 * 192, hid_b + (size_t)i * 128,      \
        Wr + (size_t)i * 64 * 64, res_b + (size_t)i * 64,                     \
        mix_w + (size_t)i * 64, out, zerobuf, x, in_w, in_b)

    for (int i = 0; i < NL; i++) {
        if (i == 0) {
            LL(1, true, false);
        } else if (i == NL - 1) {
            LL(256, false, true);
        } else {
            switch (dils[i]) {
                case 1:   LL(1, false, false);   break;
                case 2:   LL(2, false, false);   break;
                case 4:   LL(4, false, false);   break;
                case 8:   LL(8, false, false);   break;
                case 16:  LL(16, false, false);  break;
                case 32:  LL(32, false, false);  break;
                case 64:  LL(64, false, false);  break;
                case 128: LL(128, false, false); break;
                case 256: LL(256, false, false); break;
            }
        }
        const unsigned short* tH = srcH; srcH = dstH; dstH = (unsigned short*)tH;
    }
#undef LL
}

// Round 13
// 349.061 us; speedup vs baseline: 2.7487x; 1.0711x over previous
//
#include <hip/hip_runtime.h>
#include <math.h>

#define T_LEN 32768
#define NB 4
#define NC 64
#define NL 18

typedef __attribute__((ext_vector_type(8))) short s16x8;
typedef __attribute__((ext_vector_type(4))) float f32x4;
#define MFMA_F16 __builtin_amdgcn_mfma_f32_16x16x32_f16

// raw barriers: never drain vmcnt mid-pipeline (T3/T4).
#define BAR_LGKM()                                                   \
    do {                                                             \
        asm volatile("s_waitcnt lgkmcnt(0)" ::: "memory");           \
        __builtin_amdgcn_s_barrier();                                \
        __builtin_amdgcn_sched_barrier(0);                           \
    } while (0)
#define BAR_VM(N)                                                    \
    do {                                                             \
        asm volatile("s_waitcnt vmcnt(%0) lgkmcnt(0)" ::             \
                         "i"(N) : "memory");                         \
        __builtin_amdgcn_s_barrier();                                \
        __builtin_amdgcn_sched_barrier(0);                           \
    } while (0)

__device__ inline unsigned short f2h(float f) {
    _Float16 h = (_Float16)f;       // RNE
    return __builtin_bit_cast(unsigned short, h);
}
__device__ inline unsigned pack_h2(float a, float b) {
    return (unsigned)f2h(a) | ((unsigned)f2h(b) << 16);
}
__device__ inline float h2f(unsigned short u) {
    return (float)__builtin_bit_cast(_Float16, u);
}
__device__ inline float fast_sigmoid(float x) {
    return __builtin_amdgcn_rcpf(1.f + __expf(-x));
}
__device__ inline float fast_tanh(float x) {
    return 1.f - 2.f * __builtin_amdgcn_rcpf(1.f + __expf(2.f * x));
}

// ------------------------------------------------------------------
// prep: weights -> fp16; out init = mix_b; zerobuf = 0
// ------------------------------------------------------------------
__global__ void prep_kernel(const float* __restrict__ hid_w,
                            const float* __restrict__ res_w,
                            const float* __restrict__ mix_b,
                            unsigned short* __restrict__ Wh,
                            unsigned short* __restrict__ Wr,
                            float* __restrict__ out,
                            float* __restrict__ zerobuf) {
    const int nW1 = NL * 128 * 192;        // 442368
    const int nW2 = NL * 64 * 64;          // 73728
    const int nOut = NB * T_LEN;           // 131072
    const int total = nW1 + nW2 + nOut + 32;
    for (int gid = blockIdx.x * blockDim.x + threadIdx.x; gid < total;
         gid += gridDim.x * blockDim.x) {
        if (gid < nW1) {
            int K = gid % 192;
            int co = (gid / 192) & 127;
            int i = gid / (192 * 128);
            int kt = K >> 6, ci = K & 63;
            Wh[gid] = f2h(hid_w[((i * 128 + co) * 64 + ci) * 3 + kt]);
        } else if (gid < nW1 + nW2) {
            int q = gid - nW1;
            int c = q & 63, co = (q >> 6) & 63, i = q >> 12;
            Wr[q] = f2h(res_w[(i * 64 + co) * 64 + c]);
        } else if (gid < nW1 + nW2 + nOut) {
            out[gid - (nW1 + nW2)] = mix_b[0];
        } else {
            zerobuf[gid - (nW1 + nW2 + nOut)] = 0.f;
        }
    }
}

// ------------------------------------------------------------------
// fused layer, persistent-shape pipeline. Grid = 512 blocks (2/CU,
// single round, no tail). Block owns one 64-t tile; loops b=0..3 as
// pipeline items: stage(b+1) issued before compute(b), double-buffered
// 24KB X regions, counted vmcnt (BAR_VM(JMAX)) keeps next item's loads
// in flight across the whole compute. Raw barriers only.
// ------------------------------------------------------------------
template <int DIL, bool FIRST, bool LAST>
__launch_bounds__(256, 4)
__global__ void layer_kernel(const unsigned short* __restrict__ actH, // fp16 in
                             unsigned short* __restrict__ outH,       // fp16 out
                             const unsigned short* __restrict__ Wh, // [128][192]
                             const float* __restrict__ hb,          // [128]
                             const unsigned short* __restrict__ Wr, // [64][64]
                             const float* __restrict__ rb,          // [64]
                             const float* __restrict__ mw,          // [64]
                             float* __restrict__ skip,              // [B][T]
                             const float* __restrict__ zerobuf,
                             const float* __restrict__ x,           // [B][T]
                             const float* __restrict__ in_w,        // [64]
                             const float* __restrict__ in_b) {      // [64]
    constexpr bool UNI = (DIL < 64);
    constexpr int R = UNI ? (64 + 2 * DIL) : 192;   // staged rows / item
    constexpr int SLOTS = R * 8;                     // 16B chunks
    constexpr int JMAX = (SLOTS + 255) / 256;        // loads per wave
    constexpr int GS_BASE = (UNI ? 128 : 0) * 128;   // Gs overlay byte base
    constexpr int OUT_BASE = (UNI ? 0 : 64) * 128;   // OutH overlay byte base
    constexpr int REG = 24576;                       // bytes per buffer

    __shared__ uint4 Xs[2 * 1536];   // double buffer
    __shared__ float Sk[256];        // skip partials [w][t]
    char* lds = (char*)Xs;

    const int tid = threadIdx.x;
    const int w = tid >> 6;
    const int l = tid & 63;
    const int lo = l & 15;
    const int hi = l >> 4;
    const int blk = blockIdx.x;
    const int tile = (blk & 7) * 64 + (blk >> 3);    // XCD-chunked swizzle
    const int t0 = tile * 64;
    const int m0 = 16 * w;
    const int c0 = m0 + 4 * hi;

    const float* xB0 = x;

    // ---- W fragments + biases once per layer ----
    s16x8 AH[2][6];
    s16x8 AR[2];
#pragma unroll
    for (int mt = 0; mt < 2; mt++) {
        const unsigned short* wp = Wh + (size_t)(m0 + 64 * mt + lo) * 192;
#pragma unroll
        for (int s = 0; s < 6; s++)
            AH[mt][s] = *(const s16x8*)(wp + 32 * s + 8 * hi);
    }
    if (!LAST) {
#pragma unroll
        for (int s = 0; s < 2; s++)
            AR[s] = *(const s16x8*)(Wr + (size_t)(m0 + lo) * 64 + 32 * s + 8 * hi);
    }
    float bA[4], bB[4], rbv[4];
#pragma unroll
    for (int r = 0; r < 4; r++) {
        bA[r] = hb[c0 + r];
        bB[r] = hb[64 + c0 + r];
        rbv[r] = LAST ? 0.f : rb[c0 + r];
    }
    const float4 mw4 = *(const float4*)(mw + c0);

    // ---- staging lambdas ----
    auto stage_async = [&](int bb, char* X) {
        const unsigned short* aB = actH + (size_t)bb * T_LEN * NC;
#pragma unroll
        for (int jj = 0; jj < JMAX; jj++) {
            int s = (w * JMAX + jj) * 64 + l;
            const void* src;
            if (s >= SLOTS) {
                src = (const void*)(zerobuf + (s & 7) * 4);
            } else {
                int row = s >> 3, ch = s & 7;
                int chunk = ch ^ (row & 7);
                int tg = t0 + (UNI ? (row - 2 * DIL)
                                   : (((row >> 6) - 2) * DIL + (row & 63)));
                src = (tg >= 0)
                          ? (const void*)(aB + (size_t)tg * 64 + chunk * 8)
                          : (const void*)(zerobuf + chunk * 4);
            }
            __builtin_amdgcn_global_load_lds(
                (const __attribute__((address_space(1))) unsigned int*)src,
                (__attribute__((address_space(3))) unsigned int*)(X +
                                                        (w * JMAX + jj) * 1024),
                16, 0, 0);
        }
    };
    auto stage_first = [&](int bb, char* X) {
        const float* xB = xB0 + (size_t)bb * T_LEN;
#pragma unroll
        for (int jj = 0; jj < JMAX; jj++) {
            int p = jj * 256 + tid;
            if (p < SLOTS) {
                int row = p >> 3, ch = p & 7;
                int tg = t0 + row - 2 * DIL;
                unsigned uu[4] = {0u, 0u, 0u, 0u};
                if (tg >= 0) {
                    float a = xB[tg];
#pragma unroll
                    for (int e = 0; e < 4; e++) {
                        float v0 = a * in_w[ch * 8 + 2 * e] + in_b[ch * 8 + 2 * e];
                        float v1 = a * in_w[ch * 8 + 2 * e + 1] + in_b[ch * 8 + 2 * e + 1];
                        uu[e] = pack_h2(v0, v1);
                    }
                }
                int byte = (row * 128 + ch * 16) ^ ((row & 7) << 4);
                *(uint4*)(X + byte) = make_uint4(uu[0], uu[1], uu[2], uu[3]);
            }
        }
    };

    // ---- prologue: stage item 0 ----
    if (FIRST) stage_first(0, lds);
    else       stage_async(0, lds);

    // ---- 4-item pipeline over batches ----
#pragma unroll
    for (int j = 0; j < NB; j++) {
        char* X = lds + (j & 1) * REG;
        const int b = j;

        // stage next item into the other buffer (freed by item j-1)
        if (j + 1 < NB) {
            if (FIRST) stage_first(j + 1, lds + ((j + 1) & 1) * REG);
            else       stage_async(j + 1, lds + ((j + 1) & 1) * REG);
        }

        if (FIRST)          BAR_LGKM();
        else if (j + 1 < NB) BAR_VM(JMAX);   // item j ready; j+1 in flight
        else                 BAR_VM(0);

        // ---- hid GEMM over K=192 ----
        f32x4 acc[2][4];
#pragma unroll
        for (int mt = 0; mt < 2; mt++)
#pragma unroll
            for (int nt = 0; nt < 4; nt++)
                acc[mt][nt] = (f32x4){0.f, 0.f, 0.f, 0.f};
#pragma unroll
        for (int s = 0; s < 6; s++) {
            const int tap = s >> 1, half = s & 1;
#pragma unroll
            for (int nt = 0; nt < 4; nt++) {
                int t = 16 * nt + lo;
                int row = UNI ? (t + tap * DIL) : (tap * 64 + t);
                int byte = (row * 128 + half * 64 + hi * 16) ^ ((row & 7) << 4);
                s16x8 bx = __builtin_bit_cast(s16x8, *(const uint4*)(X + byte));
                acc[0][nt] = MFMA_F16(AH[0][s], bx, acc[0][nt], 0, 0, 0);
                acc[1][nt] = MFMA_F16(AH[1][s], bx, acc[1][nt], 0, 0, 0);
            }
        }

        // ---- residual input from staged tap-2 rows ----
        float4 inp[4];
        if (!LAST) {
#pragma unroll
            for (int nt = 0; nt < 4; nt++) {
                int t = 16 * nt + lo;
                int rowI = UNI ? (t + 2 * DIL) : (128 + t);
                int byteI = (rowI * 128 + c0 * 2) ^ ((rowI & 7) << 4);
                uint2 hv = *(const uint2*)(X + byteI);
                inp[nt] = make_float4(h2f((unsigned short)(hv.x & 0xffff)),
                                      h2f((unsigned short)(hv.x >> 16)),
                                      h2f((unsigned short)(hv.y & 0xffff)),
                                      h2f((unsigned short)(hv.y >> 16)));
            }
        }

        BAR_LGKM();   // all X reads done -> overlay writes safe

        // ---- gating -> Gs overlay + skip partials ----
#pragma unroll
        for (int nt = 0; nt < 4; nt++) {
            float g[4];
#pragma unroll
            for (int r = 0; r < 4; r++) {
                float hA = acc[0][nt][r] + bA[r];
                float hB = acc[1][nt][r] + bB[r];
                g[r] = fast_tanh(hA) * fast_sigmoid(hB);
            }
            int t = 16 * nt + lo;
            if (!LAST) {
                int byte = (t * 128 + c0 * 2) ^ ((t & 7) << 4);
                *(uint2*)(X + GS_BASE + byte) =
                    make_uint2(pack_h2(g[0], g[1]), pack_h2(g[2], g[3]));
            }
            float sk = g[0] * mw4.x + g[1] * mw4.y + g[2] * mw4.z + g[3] * mw4.w;
            sk += __shfl_xor(sk, 16, 64);
            sk += __shfl_xor(sk, 32, 64);
            if (hi == 0) Sk[w * 64 + nt * 16 + lo] = sk;
        }
        BAR_LGKM();

        if (LAST) {
            if (tid < 64) {
                float s2 = Sk[tid] + Sk[64 + tid] + Sk[128 + tid] + Sk[192 + tid];
                skip[(size_t)b * T_LEN + t0 + tid] += s2;
            }
            BAR_LGKM();   // Sk/buffer hygiene for next item
            continue;
        }

        // ---- res GEMM over K=64 ----
        f32x4 acc2[4];
#pragma unroll
        for (int nt = 0; nt < 4; nt++) acc2[nt] = (f32x4){0.f, 0.f, 0.f, 0.f};
#pragma unroll
        for (int s = 0; s < 2; s++) {
#pragma unroll
            for (int nt = 0; nt < 4; nt++) {
                int t = 16 * nt + lo;
                int byte = (t * 128 + s * 64 + hi * 16) ^ ((t & 7) << 4);
                s16x8 bg = __builtin_bit_cast(
                    s16x8, *(const uint4*)(X + GS_BASE + byte));
                acc2[nt] = MFMA_F16(AR[s], bg, acc2[nt], 0, 0, 0);
            }
        }

        // ---- out-stage into OutH overlay ----
        char* OutH = X + OUT_BASE;
#pragma unroll
        for (int nt = 0; nt < 4; nt++) {
            int t = 16 * nt + lo;
            float ox = acc2[nt][0] + rbv[0] + inp[nt].x;
            float oy = acc2[nt][1] + rbv[1] + inp[nt].y;
            float oz = acc2[nt][2] + rbv[2] + inp[nt].z;
            float ow = acc2[nt][3] + rbv[3] + inp[nt].w;
            int byteB = (t * 128 + c0 * 2) ^ ((t & 7) << 4);
            *(uint2*)(OutH + byteB) =
                make_uint2(pack_h2(ox, oy), pack_h2(oz, ow));
        }

        // ---- skip: one plain += per t ----
        if (tid < 64) {
            float s2 = Sk[tid] + Sk[64 + tid] + Sk[128 + tid] + Sk[192 + tid];
            skip[(size_t)b * T_LEN + t0 + tid] += s2;
        }
        BAR_LGKM();

        // ---- coalesced copy-out: full 128B lines ----
        unsigned short* gH = outH + (size_t)b * T_LEN * NC + (size_t)t0 * 64;
#pragma unroll
        for (int i = 0; i < 2; i++) {
            int u = i * 256 + tid;      // 512 uint4 = 8 KB
            int t = u >> 3, ch = u & 7;
            uint4 v = *(const uint4*)(OutH + t * 128 + ((ch ^ (t & 7)) << 4));
            ((uint4*)gH)[u] = v;
        }
        BAR_LGKM();   // all reads of this buffer done -> next stage may reuse
    }
}

// ------------------------------------------------------------------
extern "C" void kernel_launch(void* const* d_in, const int* in_sizes, int n_in,
                              void* d_out, int out_size, void* d_ws, size_t ws_size,
                              hipStream_t stream) {
    const float* x     = (const float*)d_in[0];
    const float* in_w  = (const float*)d_in[1];
    const float* in_b  = (const float*)d_in[2];
    const float* hid_w = (const float*)d_in[3];
    const float* hid_b = (const float*)d_in[4];
    const float* res_w = (const float*)d_in[5];
    const float* res_b = (const float*)d_in[6];
    const float* mix_w = (const float*)d_in[7];
    const float* mix_b = (const float*)d_in[8];
    float* out = (float*)d_out;

    const size_t actN = (size_t)NB * T_LEN * NC;  // 8388608
    unsigned short* H0 = (unsigned short*)d_ws;
    unsigned short* H1 = H0 + actN;
    unsigned short* Wh = H1 + actN;
    unsigned short* Wr = Wh + (size_t)NL * 128 * 192;
    float* zerobuf = (float*)(Wr + (size_t)NL * 64 * 64);

    prep_kernel<<<512, 256, 0, stream>>>(hid_w, res_w, mix_b, Wh, Wr, out,
                                         zerobuf);

    static const int dils[NL] = {1, 2, 4, 8, 16, 32, 64, 128, 256,
                                 1, 2, 4, 8, 16, 32, 64, 128, 256};
    const unsigned short* srcH = H0;
    unsigned short* dstH = H1;

#define LL(D, F, L)                                                           \
    layer_kernel<D, F, L><<<512, 256, 0, stream>>>(                           \
        srcH, dstH, Wh + (size_t)i * 128 * 192, hid_b + (size_t)i * 128,      \
        Wr + (size_t)i * 64 * 64, res_b + (size_t)i * 64,                     \
        mix_w + (size_t)i * 64, out, zerobuf, x, in_w, in_b)

    for (int i = 0; i < NL; i++) {
        if (i == 0) {
            LL(1, true, false);
        } else if (i == NL - 1) {
            LL(256, false, true);
        } else {
            switch (dils[i]) {
                case 1:   LL(1, false, false);   break;
                case 2:   LL(2, false, false);   break;
                case 4:   LL(4, false, false);   break;
                case 8:   LL(8, false, false);   break;
                case 16:  LL(16, false, false);  break;
                case 32:  LL(32, false, false);  break;
                case 64:  LL(64, false, false);  break;
                case 128: LL(128, false, false); break;
                case 256: LL(256, false, false); break;
            }
        }
        const unsigned short* tH = srcH; srcH = dstH; dstH = (unsigned short*)tH;
    }
#undef LL
}

// Round 15
// 347.839 us; speedup vs baseline: 2.7583x; 1.0035x over previous
//
#include <hip/hip_runtime.h>
#include <hip/hip_cooperative_groups.h>
#include <math.h>

namespace cg = cooperative_groups;

#define T_LEN 32768
#define NB 4
#define NC 64
#define NL 18

typedef __attribute__((ext_vector_type(8))) short s16x8;
typedef __attribute__((ext_vector_type(4))) float f32x4;
#define MFMA_F16 __builtin_amdgcn_mfma_f32_16x16x32_f16

// raw barriers: never drain vmcnt mid-pipeline (T3/T4).
#define BAR_LGKM()                                                   \
    do {                                                             \
        asm volatile("s_waitcnt lgkmcnt(0)" ::: "memory");           \
        __builtin_amdgcn_s_barrier();                                \
        __builtin_amdgcn_sched_barrier(0);                           \
    } while (0)
#define BAR_VM(N)                                                    \
    do {                                                             \
        asm volatile("s_waitcnt vmcnt(%0) lgkmcnt(0)" ::             \
                         "i"(N) : "memory");                         \
        __builtin_amdgcn_s_barrier();                                \
        __builtin_amdgcn_sched_barrier(0);                           \
    } while (0)

__device__ inline unsigned short f2h(float f) {
    _Float16 h = (_Float16)f;       // RNE
    return __builtin_bit_cast(unsigned short, h);
}
__device__ inline unsigned pack_h2(float a, float b) {
    return (unsigned)f2h(a) | ((unsigned)f2h(b) << 16);
}
__device__ inline float h2f(unsigned short u) {
    return (float)__builtin_bit_cast(_Float16, u);
}
__device__ inline float fast_sigmoid(float x) {
    return __builtin_amdgcn_rcpf(1.f + __expf(-x));
}
__device__ inline float fast_tanh(float x) {
    return 1.f - 2.f * __builtin_amdgcn_rcpf(1.f + __expf(2.f * x));
}

// ------------------------------------------------------------------
// prep: weights -> fp16; out init = mix_b; zerobuf = 0
// ------------------------------------------------------------------
__global__ void prep_kernel(const float* __restrict__ hid_w,
                            const float* __restrict__ res_w,
                            const float* __restrict__ mix_b,
                            unsigned short* __restrict__ Wh,
                            unsigned short* __restrict__ Wr,
                            float* __restrict__ out,
                            float* __restrict__ zerobuf) {
    const int nW1 = NL * 128 * 192;        // 442368
    const int nW2 = NL * 64 * 64;          // 73728
    const int nOut = NB * T_LEN;           // 131072
    const int total = nW1 + nW2 + nOut + 48;
    for (int gid = blockIdx.x * blockDim.x + threadIdx.x; gid < total;
         gid += gridDim.x * blockDim.x) {
        if (gid < nW1) {
            int K = gid % 192;
            int co = (gid / 192) & 127;
            int i = gid / (192 * 128);
            int kt = K >> 6, ci = K & 63;
            Wh[gid] = f2h(hid_w[((i * 128 + co) * 64 + ci) * 3 + kt]);
        } else if (gid < nW1 + nW2) {
            int q = gid - nW1;
            int c = q & 63, co = (q >> 6) & 63, i = q >> 12;
            Wr[q] = f2h(res_w[(i * 64 + co) * 64 + c]);
        } else if (gid < nW1 + nW2 + nOut) {
            out[gid - (nW1 + nW2)] = mix_b[0];
        } else {
            zerobuf[gid - (nW1 + nW2 + nOut)] = 0.f;
        }
    }
}

// ------------------------------------------------------------------
// one layer body (verified R13 kernel body). 4-item batch pipeline,
// double-buffered 24KB X regions, counted vmcnt.
// ------------------------------------------------------------------
template <int DIL>
__device__ __forceinline__ void layer_body(
    const bool first, const bool last,
    const unsigned short* actH, unsigned short* outH,
    const unsigned short* Wh, const float* hb,
    const unsigned short* Wr, const float* rb,
    const float* mw, float* skip,
    const float* zerobuf, const float* x,
    const float* in_w, const float* in_b,
    char* lds, float* Sk, const int t0)
{
    constexpr bool UNI = (DIL < 64);
    constexpr int R = UNI ? (64 + 2 * DIL) : 192;
    constexpr int SLOTS = R * 8;
    constexpr int JMAX = (SLOTS + 255) / 256;
    constexpr int GS_BASE = (UNI ? 128 : 0) * 128;
    constexpr int OUT_BASE = (UNI ? 0 : 64) * 128;
    constexpr int REG = 24576;

    const int tid = threadIdx.x;
    const int w = tid >> 6;
    const int l = tid & 63;
    const int lo = l & 15;
    const int hi = l >> 4;
    const int m0 = 16 * w;
    const int c0 = m0 + 4 * hi;

    // ---- W fragments + biases ----
    s16x8 AH[2][6];
    s16x8 AR[2];
#pragma unroll
    for (int mt = 0; mt < 2; mt++) {
        const unsigned short* wp = Wh + (size_t)(m0 + 64 * mt + lo) * 192;
#pragma unroll
        for (int s = 0; s < 6; s++)
            AH[mt][s] = *(const s16x8*)(wp + 32 * s + 8 * hi);
    }
    if (!(DIL == 256 && last)) {
#pragma unroll
        for (int s = 0; s < 2; s++)
            AR[s] = *(const s16x8*)(Wr + (size_t)(m0 + lo) * 64 + 32 * s + 8 * hi);
    }
    float bA[4], bB[4], rbv[4];
#pragma unroll
    for (int r = 0; r < 4; r++) {
        bA[r] = hb[c0 + r];
        bB[r] = hb[64 + c0 + r];
        rbv[r] = (DIL == 256 && last) ? 0.f : rb[c0 + r];
    }
    const float4 mw4 = *(const float4*)(mw + c0);

    auto stage_async = [&](int bb, char* X) {
        const unsigned short* aB = actH + (size_t)bb * T_LEN * NC;
#pragma unroll
        for (int jj = 0; jj < JMAX; jj++) {
            int s = (w * JMAX + jj) * 64 + l;
            const void* src;
            if (s >= SLOTS) {
                src = (const void*)(zerobuf + (s & 7) * 4);
            } else {
                int row = s >> 3, ch = s & 7;
                int chunk = ch ^ (row & 7);
                int tg = t0 + (UNI ? (row - 2 * DIL)
                                   : (((row >> 6) - 2) * DIL + (row & 63)));
                src = (tg >= 0)
                          ? (const void*)(aB + (size_t)tg * 64 + chunk * 8)
                          : (const void*)(zerobuf + chunk * 4);
            }
            __builtin_amdgcn_global_load_lds(
                (const __attribute__((address_space(1))) unsigned int*)src,
                (__attribute__((address_space(3))) unsigned int*)(X +
                                                        (w * JMAX + jj) * 1024),
                16, 0, 0);
        }
    };
    auto stage_first = [&](int bb, char* X) {
        const float* xB = x + (size_t)bb * T_LEN;
#pragma unroll
        for (int jj = 0; jj < JMAX; jj++) {
            int p = jj * 256 + tid;
            if (p < SLOTS) {
                int row = p >> 3, ch = p & 7;
                int tg = t0 + row - 2 * DIL;
                unsigned uu[4] = {0u, 0u, 0u, 0u};
                if (tg >= 0) {
                    float a = xB[tg];
#pragma unroll
                    for (int e = 0; e < 4; e++) {
                        float v0 = a * in_w[ch * 8 + 2 * e] + in_b[ch * 8 + 2 * e];
                        float v1 = a * in_w[ch * 8 + 2 * e + 1] + in_b[ch * 8 + 2 * e + 1];
                        uu[e] = pack_h2(v0, v1);
                    }
                }
                int byte = (row * 128 + ch * 16) ^ ((row & 7) << 4);
                *(uint4*)(X + byte) = make_uint4(uu[0], uu[1], uu[2], uu[3]);
            }
        }
    };

    // ---- prologue: stage item 0 ----
    if (DIL == 1 && first) stage_first(0, lds);
    else                   stage_async(0, lds);

    // ---- 4-item pipeline over batches ----
#pragma unroll
    for (int j = 0; j < NB; j++) {
        char* X = lds + (j & 1) * REG;
        const int b = j;

        if (j + 1 < NB) {
            if (DIL == 1 && first) stage_first(j + 1, lds + ((j + 1) & 1) * REG);
            else                   stage_async(j + 1, lds + ((j + 1) & 1) * REG);
        }

        if (DIL == 1 && first) { BAR_LGKM(); }
        else if (j + 1 < NB)   { BAR_VM(JMAX); }
        else                   { BAR_VM(0); }

        // ---- hid GEMM over K=192 ----
        f32x4 acc[2][4];
#pragma unroll
        for (int mt = 0; mt < 2; mt++)
#pragma unroll
            for (int nt = 0; nt < 4; nt++)
                acc[mt][nt] = (f32x4){0.f, 0.f, 0.f, 0.f};
#pragma unroll
        for (int s = 0; s < 6; s++) {
            const int tap = s >> 1, half = s & 1;
#pragma unroll
            for (int nt = 0; nt < 4; nt++) {
                int t = 16 * nt + lo;
                int row = UNI ? (t + tap * DIL) : (tap * 64 + t);
                int byte = (row * 128 + half * 64 + hi * 16) ^ ((row & 7) << 4);
                s16x8 bx = __builtin_bit_cast(s16x8, *(const uint4*)(X + byte));
                acc[0][nt] = MFMA_F16(AH[0][s], bx, acc[0][nt], 0, 0, 0);
                acc[1][nt] = MFMA_F16(AH[1][s], bx, acc[1][nt], 0, 0, 0);
            }
        }

        // ---- residual input from staged tap-2 rows ----
        float4 inp[4];
        if (!(DIL == 256 && last)) {
#pragma unroll
            for (int nt = 0; nt < 4; nt++) {
                int t = 16 * nt + lo;
                int rowI = UNI ? (t + 2 * DIL) : (128 + t);
                int byteI = (rowI * 128 + c0 * 2) ^ ((rowI & 7) << 4);
                uint2 hv = *(const uint2*)(X + byteI);
                inp[nt] = make_float4(h2f((unsigned short)(hv.x & 0xffff)),
                                      h2f((unsigned short)(hv.x >> 16)),
                                      h2f((unsigned short)(hv.y & 0xffff)),
                                      h2f((unsigned short)(hv.y >> 16)));
            }
        }

        BAR_LGKM();   // all X reads done -> overlay writes safe

        // ---- gating -> Gs overlay + skip partials ----
#pragma unroll
        for (int nt = 0; nt < 4; nt++) {
            float g[4];
#pragma unroll
            for (int r = 0; r < 4; r++) {
                float hA = acc[0][nt][r] + bA[r];
                float hB = acc[1][nt][r] + bB[r];
                g[r] = fast_tanh(hA) * fast_sigmoid(hB);
            }
            int t = 16 * nt + lo;
            if (!(DIL == 256 && last)) {
                int byte = (t * 128 + c0 * 2) ^ ((t & 7) << 4);
                *(uint2*)(X + GS_BASE + byte) =
                    make_uint2(pack_h2(g[0], g[1]), pack_h2(g[2], g[3]));
            }
            float sk = g[0] * mw4.x + g[1] * mw4.y + g[2] * mw4.z + g[3] * mw4.w;
            sk += __shfl_xor(sk, 16, 64);
            sk += __shfl_xor(sk, 32, 64);
            if (hi == 0) Sk[w * 64 + nt * 16 + lo] = sk;
        }
        BAR_LGKM();

        if (DIL == 256 && last) {
            if (tid < 64) {
                float s2 = Sk[tid] + Sk[64 + tid] + Sk[128 + tid] + Sk[192 + tid];
                skip[(size_t)b * T_LEN + t0 + tid] += s2;
            }
            BAR_LGKM();
            continue;
        }

        // ---- res GEMM over K=64 ----
        f32x4 acc2[4];
#pragma unroll
        for (int nt = 0; nt < 4; nt++) acc2[nt] = (f32x4){0.f, 0.f, 0.f, 0.f};
#pragma unroll
        for (int s = 0; s < 2; s++) {
#pragma unroll
            for (int nt = 0; nt < 4; nt++) {
                int t = 16 * nt + lo;
                int byte = (t * 128 + s * 64 + hi * 16) ^ ((t & 7) << 4);
                s16x8 bg = __builtin_bit_cast(
                    s16x8, *(const uint4*)(X + GS_BASE + byte));
                acc2[nt] = MFMA_F16(AR[s], bg, acc2[nt], 0, 0, 0);
            }
        }

        // ---- out-stage into OutH overlay ----
        char* OutH = X + OUT_BASE;
#pragma unroll
        for (int nt = 0; nt < 4; nt++) {
            int t = 16 * nt + lo;
            float ox = acc2[nt][0] + rbv[0] + inp[nt].x;
            float oy = acc2[nt][1] + rbv[1] + inp[nt].y;
            float oz = acc2[nt][2] + rbv[2] + inp[nt].z;
            float ow = acc2[nt][3] + rbv[3] + inp[nt].w;
            int byteB = (t * 128 + c0 * 2) ^ ((t & 7) << 4);
            *(uint2*)(OutH + byteB) =
                make_uint2(pack_h2(ox, oy), pack_h2(oz, ow));
        }

        // ---- skip: one plain += per t ----
        if (tid < 64) {
            float s2 = Sk[tid] + Sk[64 + tid] + Sk[128 + tid] + Sk[192 + tid];
            skip[(size_t)b * T_LEN + t0 + tid] += s2;
        }
        BAR_LGKM();

        // ---- coalesced copy-out: full 128B lines ----
        unsigned short* gH = outH + (size_t)b * T_LEN * NC + (size_t)t0 * 64;
#pragma unroll
        for (int i = 0; i < 2; i++) {
            int u = i * 256 + tid;
            int t = u >> 3, ch = u & 7;
            uint4 v = *(const uint4*)(OutH + t * 128 + ((ch ^ (t & 7)) << 4));
            ((uint4*)gH)[u] = v;
        }
        BAR_LGKM();
    }
}

// ------------------------------------------------------------------
// fallback per-layer kernel (== R13, known-good @349us)
// ------------------------------------------------------------------
template <int DIL, bool FIRST, bool LAST>
__launch_bounds__(256, 4)
__global__ void layer_kernel(const unsigned short* actH, unsigned short* outH,
                             const unsigned short* Wh, const float* hb,
                             const unsigned short* Wr, const float* rb,
                             const float* mw, float* skip,
                             const float* zerobuf, const float* x,
                             const float* in_w, const float* in_b) {
    __shared__ uint4 Xs[2 * 1536];
    __shared__ float Sk[256];
    const int blk = blockIdx.x;
    const int tile = (blk & 7) * 64 + (blk >> 3);
    layer_body<DIL>(FIRST, LAST, actH, outH, Wh, hb, Wr, rb, mw, skip,
                    zerobuf, x, in_w, in_b, (char*)Xs, Sk, tile * 64);
}

// ------------------------------------------------------------------
// megakernel: all 18 layers, cg::grid sync (vendor-validated cache
// coherence protocol) between layers. 512 blocks cooperative.
// ------------------------------------------------------------------
__launch_bounds__(256, 4)
__global__ void mega_kernel(const unsigned short* H0, unsigned short* H1,
                            const unsigned short* Wh, const float* hid_b,
                            const unsigned short* Wr, const float* res_b,
                            const float* mix_w, float* out,
                            const float* zerobuf, const float* x,
                            const float* in_w, const float* in_b)
{
    __shared__ uint4 Xs[2 * 1536];
    __shared__ float Sk[256];
    char* lds = (char*)Xs;

    cg::grid_group grid = cg::this_grid();

    const int blk = blockIdx.x;
    const int tile = (blk & 7) * 64 + (blk >> 3);   // XCD-chunked swizzle
    const int t0 = tile * 64;

    const unsigned short* src = H0;
    unsigned short* dst = H1;

    for (int r = 0; r < 2; r++) {
#define LBODY(K, D)                                                          \
        {                                                                    \
            const int li = r * 9 + K;                                        \
            const bool first = (D == 1) && (li == 0);                        \
            const bool last = (D == 256) && (r == 1);                        \
            layer_body<D>(first, last, src, dst,                             \
                          Wh + (size_t)li * 128 * 192, hid_b + li * 128,     \
                          Wr + (size_t)li * 64 * 64, res_b + li * 64,        \
                          mix_w + li * 64, out, zerobuf, x, in_w, in_b,      \
                          lds, Sk, t0);                                      \
            if (!last) {                                                     \
                grid.sync();                                                 \
                const unsigned short* tt = src;                              \
                src = dst;                                                   \
                dst = (unsigned short*)tt;                                   \
            }                                                                \
        }
        LBODY(0, 1) LBODY(1, 2) LBODY(2, 4) LBODY(3, 8) LBODY(4, 16)
        LBODY(5, 32) LBODY(6, 64) LBODY(7, 128) LBODY(8, 256)
#undef LBODY
    }
}

// ------------------------------------------------------------------
extern "C" void kernel_launch(void* const* d_in, const int* in_sizes, int n_in,
                              void* d_out, int out_size, void* d_ws, size_t ws_size,
                              hipStream_t stream) {
    const float* x     = (const float*)d_in[0];
    const float* in_w  = (const float*)d_in[1];
    const float* in_b  = (const float*)d_in[2];
    const float* hid_w = (const float*)d_in[3];
    const float* hid_b = (const float*)d_in[4];
    const float* res_w = (const float*)d_in[5];
    const float* res_b = (const float*)d_in[6];
    const float* mix_w = (const float*)d_in[7];
    const float* mix_b = (const float*)d_in[8];
    float* out = (float*)d_out;

    const size_t actN = (size_t)NB * T_LEN * NC;  // 8388608
    unsigned short* H0 = (unsigned short*)d_ws;
    unsigned short* H1 = H0 + actN;
    unsigned short* Wh = H1 + actN;
    unsigned short* Wr = Wh + (size_t)NL * 128 * 192;
    float* zerobuf = (float*)(Wr + (size_t)NL * 64 * 64);

    prep_kernel<<<512, 256, 0, stream>>>(hid_w, res_w, mix_b, Wh, Wr, out,
                                         zerobuf);

    // occupancy precheck (host-side, deterministic, capture-safe)
    int nbPerCU = 0;
    hipError_t oe = hipOccupancyMaxActiveBlocksPerMultiprocessor(
        &nbPerCU, mega_kernel, 256, 0);
    bool coop = (oe == hipSuccess) && (nbPerCU >= 2);

    if (coop) {
        const unsigned short* a0 = H0;
        unsigned short* a1 = H1;
        const unsigned short* a2 = Wh;
        const float* a3 = hid_b;
        const unsigned short* a4 = Wr;
        const float* a5 = res_b;
        const float* a6 = mix_w;
        float* a7 = out;
        const float* a8 = zerobuf;
        const float* a9 = x;
        const float* a10 = in_w;
        const float* a11 = in_b;
        void* args[12] = {&a0, &a1, &a2, &a3, &a4, &a5,
                          &a6, &a7, &a8, &a9, &a10, &a11};
        hipError_t le = hipLaunchCooperativeKernel(
            (void*)mega_kernel, dim3(512), dim3(256), args, 0, stream);
        if (le == hipSuccess) return;
        coop = false;   // fall through to multi-kernel path
    }

    // fallback: R13 multi-kernel loop (known-good)
    const unsigned short* srcH = H0;
    unsigned short* dstH = H1;
#define LL(D, F, L)                                                           \
    layer_kernel<D, F, L><<<512, 256, 0, stream>>>(                           \
        srcH, dstH, Wh + (size_t)i * 128 * 192, hid_b + (size_t)i * 128,      \
        Wr + (size_t)i * 64 * 64, res_b + (size_t)i * 64,                     \
        mix_w + (size_t)i * 64, out, zerobuf, x, in_w, in_b)

    static const int dils[NL] = {1, 2, 4, 8, 16, 32, 64, 128, 256,
                                 1, 2, 4, 8, 16, 32, 64, 128, 256};
    for (int i = 0; i < NL; i++) {
        if (i == 0) {
            LL(1, true, false);
        } else if (i == NL - 1) {
            LL(256, false, true);
        } else {
            switch (dils[i]) {
                case 1:   LL(1, false, false);   break;
                case 2:   LL(2, false, false);   break;
                case 4:   LL(4, false, false);   break;
                case 8:   LL(8, false, false);   break;
                case 16:  LL(16, false, false);  break;
                case 32:  LL(32, false, false);  break;
                case 64:  LL(64, false, false);  break;
                case 128: LL(128, false, false); break;
                case 256: LL(256, false, false); break;
            }
        }
        const unsigned short* tH = srcH; srcH = dstH; dstH = (unsigned short*)tH;
    }
#undef LL
}